// Round 6
// baseline (617.383 us; speedup 1.0000x reference)
//
#include <hip/hip_runtime.h>

using u16 = unsigned short;
typedef float f32x4 __attribute__((ext_vector_type(4)));
typedef __bf16 bf16x8 __attribute__((ext_vector_type(8)));
typedef u16 u16x8 __attribute__((ext_vector_type(8)));
typedef u16 u16x4 __attribute__((ext_vector_type(4)));

// dims: B=64, S=2048, ENC=1024, U=512, E=256, V=50000, IN=1280
// scratch layout (float units)
static constexpr int OF_HPB   = 262144;    // w1p: 512K u16 = 262144 floats
static constexpr int OF_SCORE = 294912;    // hpb: 64*512
static constexpr int OF_XIN   = 425984;    // score: 64*2048
static constexpr int OF_ZPART = 507904;    // xin: 64*1280
static constexpr size_t SCRATCH_FLOATS = 1032192;   // + zpart 4*64*2048
static constexpr size_t SCRATCH_BYTES  = SCRATCH_FLOATS * 4ull;
static constexpr size_t OF_W2P_F       = 1032192;              // float offset of w2p
static constexpr size_t W2P_U16        = 50176ull * 1024ull;   // padded-N bf16 fc_w
static constexpr size_t TOTAL_BYTES    = OF_W2P_F * 4ull + W2P_U16 * 2ull;  // ~102 MB

__device__ __forceinline__ u16 f2bf(float f) {
  unsigned u = __float_as_uint(f);
  u += 0x7FFFu + ((u >> 16) & 1u);   // RNE; inputs finite
  return (u16)(u >> 16);
}
__device__ __forceinline__ float bf2f(u16 u) {
  return __uint_as_float((unsigned)u << 16);
}
__device__ __forceinline__ float fast_tanh(float x) {
  x = fminf(fmaxf(x, -20.f), 20.f);
  float e = __expf(2.f * x);
  return (e - 1.f) / (e + 1.f);
}
__device__ __forceinline__ float fast_sig(float x) { return 1.f / (1.f + __expf(-x)); }

__device__ __forceinline__ void gll16(const u16* g, u16* l) {
  __builtin_amdgcn_global_load_lds(
      (const __attribute__((address_space(1))) unsigned int*)g,
      (__attribute__((address_space(3))) unsigned int*)l, 16, 0, 0);
}

// ---------------- W1 (1024x512 f32 [k][u]) -> bf16 packed [ks][u][kk], ks=k/32
__global__ void k_prep_w1(const float* __restrict__ W1w, u16* __restrict__ w1p) {
  __shared__ float tile[32][132];
  const int t = threadIdx.x;
  const int ks = blockIdx.x >> 2, u0 = (blockIdx.x & 3) * 128;
  {
    int kk = t >> 3, ui = (t & 7) * 16;
    const float* src = W1w + (size_t)(ks * 32 + kk) * 512 + u0 + ui;
    #pragma unroll
    for (int i = 0; i < 4; ++i)
      *(float4*)&tile[kk][ui + i * 4] = *(const float4*)(src + i * 4);
  }
  __syncthreads();
  {
    int u = t >> 1, kh = (t & 1) * 16;
    u16x8 p0, p1;
    #pragma unroll
    for (int i = 0; i < 8; ++i) {
      p0[i] = f2bf(tile[kh + i][u]);
      p1[i] = f2bf(tile[kh + 8 + i][u]);
    }
    u16* dst = w1p + ((size_t)ks * 512 + u0 + u) * 32 + kh;
    *(u16x8*)(dst)     = p0;
    *(u16x8*)(dst + 8) = p1;
  }
}

// ---------------- hpb[b][u] = c_fwd@W2 + W2_b + c_bwd@W3 + W3_b + W1_b
__global__ void k_prep_hp(const float* __restrict__ cf, const float* __restrict__ cb,
                          const float* __restrict__ W2w, const float* __restrict__ W2b,
                          const float* __restrict__ W3w, const float* __restrict__ W3b,
                          const float* __restrict__ W1b, float* __restrict__ hpb) {
  __shared__ float cfl[512], cbl[512];
  const int b = blockIdx.x, t = threadIdx.x;
  cfl[t] = cf[(size_t)b * 512 + t];       cfl[t + 256] = cf[(size_t)b * 512 + t + 256];
  cbl[t] = cb[(size_t)b * 512 + t];       cbl[t + 256] = cb[(size_t)b * 512 + t + 256];
  __syncthreads();
  const int u1 = t, u2 = t + 256;
  float a1 = W2b[u1] + W3b[u1] + W1b[u1];
  float a2 = W2b[u2] + W3b[u2] + W1b[u2];
  for (int k = 0; k < 512; ++k) {
    float c1 = cfl[k], c2 = cbl[k];
    const float* r2 = W2w + (size_t)k * 512;
    const float* r3 = W3w + (size_t)k * 512;
    a1 += c1 * r2[u1] + c2 * r3[u1];
    a2 += c1 * r2[u2] + c2 * r3[u2];
  }
  hpb[(size_t)b * 512 + u1] = a1;
  hpb[(size_t)b * 512 + u2] = a2;
}

// ---------------- fcw (1024x50000 f32 [k][n]) -> bf16 packed [ks][j][kk], j padded to 50176
__global__ void __launch_bounds__(256)
k_prep_fcw(const float* __restrict__ fcw, u16* __restrict__ w2p) {
  __shared__ float tl[32][260];
  const int t = threadIdx.x;
  const int jt = blockIdx.x >> 5, kt = blockIdx.x & 31;
  const int j0 = jt * 256, k0 = kt * 32;
  {
    const int kk = t >> 3, c0 = (t & 7) * 32;
    const float* src = fcw + (size_t)(k0 + kk) * 50000 + j0 + c0;
    #pragma unroll
    for (int i = 0; i < 8; ++i) {
      int j = j0 + c0 + i * 4;
      float4 v;
      if (j + 3 < 50000) {
        v = *(const float4*)(src + i * 4);
      } else {
        v.x = (j + 0 < 50000) ? src[i * 4 + 0] : 0.f;
        v.y = (j + 1 < 50000) ? src[i * 4 + 1] : 0.f;
        v.z = (j + 2 < 50000) ? src[i * 4 + 2] : 0.f;
        v.w = 0.f;
      }
      *(float4*)&tl[kk][c0 + i * 4] = v;
    }
  }
  __syncthreads();
  {
    u16* dst = w2p + ((size_t)kt * 50176 + j0 + t) * 32;
    #pragma unroll
    for (int q = 0; q < 4; ++q) {
      u16x8 p;
      #pragma unroll
      for (int m = 0; m < 8; ++m) p[m] = f2bf(tl[q * 8 + m][t]);
      *(u16x8*)(dst + q * 8) = p;
    }
  }
}

// ---------------- score GEMM: score[b][s] = tanh(enc@W1 + hpb) @ Vw + Vb
// 2048 blocks = 64 b x 32 tiles (64 rows). 512 thr / 8 waves (1M x 8N, wave 64x64).
// LDS 72KB (2 blocks/CU): B dbuf 2x32KB (global_load_lds, read-contiguous chunk
// layout via pre-permuted per-lane source) + A dbuf 2x4KB (reg-staged f32->bf16,
// read-contiguous chunks). Plain __syncthreads pipeline (compiler-scheduled waits).
__global__ void __launch_bounds__(512, 4)
k_score(const float* __restrict__ enc, const u16* __restrict__ w1p,
        const float* __restrict__ hpb, const float* __restrict__ Vw,
        const float* __restrict__ Vb, float* __restrict__ score) {
  __shared__ __align__(16) u16 smem[36864];   // B0[16384] B1[16384] A0[2048] A1[2048]

  const int t = threadIdx.x;
  const int bid = blockIdx.x;
  const int b = bid >> 5, tile = bid & 31;
  const size_t row0 = (size_t)b * 2048 + (size_t)tile * 64;

  const int l = t & 63, w = t >> 6;     // 8 waves; wave w owns cols [w*64, w*64+64)
  const int ln = l & 15, lg = l >> 4;

  // A staging: thread t loads 4 f32 of row (s_im*16+s_ln), k-octet s_lg, half s_h
  const int s_im = t >> 7, s_ln = (t >> 3) & 15, s_lg = (t >> 1) & 3, s_h = t & 1;
  const float* a_src = enc + (row0 + s_im * 16 + s_ln) * 1024 + s_lg * 8 + s_h * 4;
  const int a_dst = (s_im * 64 + s_lg * 16 + s_ln) * 8 + s_h * 4;   // read-contig chunk
  // B staging: per-lane permuted source so linear gll16 writes land read-contiguous
  const u16* bsrc = w1p + (size_t)(w * 64 + ln) * 32 + lg * 8;      // + ks*16384 + nf*512
  u16* bdst = smem + w * 2048;                                       // + (buf<<14) + nf*512

  f32x4 acc[4][4];
  #pragma unroll
  for (int im = 0; im < 4; ++im)
    #pragma unroll
    for (int nf = 0; nf < 4; ++nf) acc[im][nf] = f32x4{0.f, 0.f, 0.f, 0.f};

  // prologue: stage A(0)+B(0) into buf0; A(1) in flight
  float4 avB;
  {
    float4 av0 = *(const float4*)(a_src);
    u16x4 aw;
    aw[0]=f2bf(av0.x); aw[1]=f2bf(av0.y); aw[2]=f2bf(av0.z); aw[3]=f2bf(av0.w);
    *(u16x4*)(smem + 32768 + a_dst) = aw;
    gll16(bsrc,        bdst);
    gll16(bsrc +  512, bdst +  512);
    gll16(bsrc + 1024, bdst + 1024);
    gll16(bsrc + 1536, bdst + 1536);
    avB = *(const float4*)(a_src + 32);
  }
  __syncthreads();

  for (int ks = 0; ks < 32; ++ks) {
    const int cur = ks & 1;
    if (ks < 31) {
      // stage A(ks+1) (value completed at previous barrier's implicit drain)
      u16* An = smem + 32768 + ((cur ^ 1) << 11);
      u16x4 aw;
      aw[0]=f2bf(avB.x); aw[1]=f2bf(avB.y); aw[2]=f2bf(avB.z); aw[3]=f2bf(avB.w);
      *(u16x4*)(An + a_dst) = aw;
      if (ks < 30) avB = *(const float4*)(a_src + (ks + 2) * 32);   // A(ks+2) in flight
      // issue B(ks+1)
      u16* bd = bdst + ((cur ^ 1) << 14);
      const u16* bs = bsrc + (size_t)(ks + 1) * 16384;
      gll16(bs, bd);               gll16(bs +  512, bd +  512);
      gll16(bs + 1024, bd + 1024); gll16(bs + 1536, bd + 1536);
    }
    const u16* Ac = smem + 32768 + (cur << 11);
    const u16* Bc = smem + (cur << 14) + w * 2048;
    bf16x8 afr[4], bfr[4];
    #pragma unroll
    for (int im = 0; im < 4; ++im) afr[im] = *(const bf16x8*)(Ac + im * 512 + l * 8);
    #pragma unroll
    for (int nf = 0; nf < 4; ++nf) bfr[nf] = *(const bf16x8*)(Bc + nf * 512 + l * 8);
    #pragma unroll
    for (int im = 0; im < 4; ++im)
      #pragma unroll
      for (int nf = 0; nf < 4; ++nf)
        acc[im][nf] = __builtin_amdgcn_mfma_f32_16x16x32_bf16(afr[im], bfr[nf], acc[im][nf], 0, 0, 0);
    __syncthreads();
  }

  // ---- epilogue: score_row = sum_u tanh(acc + hp[u]) * Vw[u]  (smem reused)
  float* fsm = (float*)smem;
  float* red = fsm;            // [64][9]

  float vw_l[4], hp_l[4];
  #pragma unroll
  for (int nf = 0; nf < 4; ++nf) {
    int col = w * 64 + nf * 16 + ln;
    vw_l[nf] = Vw[col];
    hp_l[nf] = hpb[(size_t)b * 512 + col];
  }
  #pragma unroll
  for (int im = 0; im < 4; ++im) {
    #pragma unroll
    for (int r = 0; r < 4; ++r) {
      float s = 0.f;
      #pragma unroll
      for (int nf = 0; nf < 4; ++nf)
        s += vw_l[nf] * fast_tanh(acc[im][nf][r] + hp_l[nf]);
      s += __shfl_xor(s, 1);
      s += __shfl_xor(s, 2);
      s += __shfl_xor(s, 4);
      s += __shfl_xor(s, 8);
      if (ln == 0) red[(im * 16 + lg * 4 + r) * 9 + w] = s;
    }
  }
  __syncthreads();
  if (t < 64) {
    float s = Vb[0];
    #pragma unroll
    for (int w2 = 0; w2 < 8; ++w2) s += red[t * 9 + w2];
    score[row0 + t] = s;
  }
}

// ---------------- softmax over S + ctx = attn @ enc  (one enc pass, no atomics)
// block = (b, 128-col tile); scores bounded (|tanh|<=1, sum|Vw| ~ 8) so raw exp is f32-safe
__global__ void k_ctx(const float* __restrict__ enc, const float* __restrict__ score,
                      float* __restrict__ xin) {
  __shared__ float esm[2048];
  __shared__ float reds[256];
  const int t = threadIdx.x;
  const int b = blockIdx.x >> 3, ct = blockIdx.x & 7;
  float p = 0.f;
  for (int s = t; s < 2048; s += 256) {
    float e = __expf(score[(size_t)b * 2048 + s]);
    esm[s] = e;
    p += e;
  }
  reds[t] = p;
  __syncthreads();
  for (int off = 128; off > 0; off >>= 1) {
    if (t < off) reds[t] += reds[t + off];
    __syncthreads();
  }
  const float inv = 1.f / reds[0];
  __syncthreads();
  const int c = ct * 128 + (t & 127);
  const int sp = t >> 7;
  const float* ep = enc + (size_t)b * 2048 * 1024 + c;
  float a0=0,a1=0,a2=0,a3=0,a4=0,a5=0,a6=0,a7=0;
  for (int s = sp; s < 2048; s += 16) {
    a0 += esm[s+ 0] * ep[(size_t)(s+ 0) * 1024];
    a1 += esm[s+ 2] * ep[(size_t)(s+ 2) * 1024];
    a2 += esm[s+ 4] * ep[(size_t)(s+ 4) * 1024];
    a3 += esm[s+ 6] * ep[(size_t)(s+ 6) * 1024];
    a4 += esm[s+ 8] * ep[(size_t)(s+ 8) * 1024];
    a5 += esm[s+10] * ep[(size_t)(s+10) * 1024];
    a6 += esm[s+12] * ep[(size_t)(s+12) * 1024];
    a7 += esm[s+14] * ep[(size_t)(s+14) * 1024];
  }
  float a = ((a0+a1)+(a2+a3)) + ((a4+a5)+(a6+a7));
  reds[t] = a;
  __syncthreads();
  if (t < 128) xin[(size_t)b * 1280 + c] = (reds[t] + reds[t + 128]) * inv;
}

// ---------------- xin[:,1024:1280] = emb[x]
__global__ void k_xe(const int* __restrict__ x, const float* __restrict__ emb,
                     float* __restrict__ xin) {
  const int b = blockIdx.x, t = threadIdx.x;
  xin[(size_t)b * 1280 + 1024 + t] = emb[(size_t)x[b] * 256 + t];
}

// ---------------- z_part = xin @ K  (dir x ksplit x jtile), f32
__global__ void k_lstm_gemm(const float* __restrict__ xin, const float* __restrict__ Kf,
                            const float* __restrict__ Kb, float* __restrict__ zpart) {
  __shared__ float xl[32][68];   // [kk][b], padded
  const int t = threadIdx.x;
  const int bid = blockIdx.x;          // 2 dir * 64 jt * 2 ks = 256
  const int dir = bid >> 7;
  const int jt  = (bid >> 1) & 63;
  const int ks  = bid & 1;
  const float* K = dir ? Kb : Kf;
  const int j  = jt * 32 + (t & 31);
  const int tb = t >> 5;               // 8 groups of 8 b
  const int brow = t >> 2, kq = (t & 3) * 8;
  float acc[8] = {0,0,0,0,0,0,0,0};
  for (int k0 = ks * 640; k0 < ks * 640 + 640; k0 += 32) {
    float4 x0 = *(const float4*)&xin[(size_t)brow * 1280 + k0 + kq];
    float4 x1 = *(const float4*)&xin[(size_t)brow * 1280 + k0 + kq + 4];
    __syncthreads();
    xl[kq+0][brow]=x0.x; xl[kq+1][brow]=x0.y; xl[kq+2][brow]=x0.z; xl[kq+3][brow]=x0.w;
    xl[kq+4][brow]=x1.x; xl[kq+5][brow]=x1.y; xl[kq+6][brow]=x1.z; xl[kq+7][brow]=x1.w;
    __syncthreads();
    const float* Kp = K + (size_t)k0 * 2048 + j;
    #pragma unroll 8
    for (int kk = 0; kk < 32; ++kk) {
      float wv = Kp[(size_t)kk * 2048];
      float4 v0 = *(const float4*)&xl[kk][tb * 8];
      float4 v1 = *(const float4*)&xl[kk][tb * 8 + 4];
      acc[0] += v0.x * wv; acc[1] += v0.y * wv; acc[2] += v0.z * wv; acc[3] += v0.w * wv;
      acc[4] += v1.x * wv; acc[5] += v1.y * wv; acc[6] += v1.z * wv; acc[7] += v1.w * wv;
    }
  }
  float* zp = zpart + ((size_t)dir * 2 + ks) * 64 * 2048;
  #pragma unroll
  for (int i = 0; i < 8; ++i)
    zp[(size_t)(tb * 8 + i) * 2048 + j] = acc[i];
}

// ---------------- gates: c = sig(i)*tanh(g); h = sig(o)*tanh(c)
__global__ void k_gates(const float* __restrict__ zpart, const float* __restrict__ bfv,
                        const float* __restrict__ bbv, float* __restrict__ dout) {
  const int dir = blockIdx.x >> 6, b = blockIdx.x & 63, u = threadIdx.x;
  const float* bias = dir ? bbv : bfv;
  const float* z0 = zpart + ((size_t)dir * 2 + 0) * 131072 + (size_t)b * 2048;
  const float* z1 = zpart + ((size_t)dir * 2 + 1) * 131072 + (size_t)b * 2048;
  float zi = z0[u]        + z1[u]        + bias[u];
  float zg = z0[1024 + u] + z1[1024 + u] + bias[1024 + u];
  float zo = z0[1536 + u] + z1[1536 + u] + bias[1536 + u];
  float c = fast_sig(zi) * fast_tanh(zg);
  float h = fast_sig(zo) * fast_tanh(c);
  size_t base = 3200000u + (size_t)dir * 65536u;
  dout[base + (size_t)b * 512 + u] = h;
  dout[base + 32768u + (size_t)b * 512 + u] = c;
}

// ---------------- logits = [hf hb] @ fc_w + fc_b  via MFMA (h hi+lo bf16, W bf16)
// 392 blocks x 128 cols. 256 thr / 4 waves (1M x 4N), wave tile 64x32. 32KB LDS
// -> ~4 blocks/CU so the per-iter barrier drains overlap across blocks.
__global__ void __launch_bounds__(256)
k_fc_mfma(const float* __restrict__ hbase, const u16* __restrict__ w2p,
          const float* __restrict__ fcb, float* __restrict__ logits) {
  __shared__ __align__(16) u16 smem[16384];  // 32KB: B0[4096] B1[4096] A0[4096] A1[4096]
  const int t = threadIdx.x;
  const int j0 = blockIdx.x * 128;
  const int l = t & 63, w = t >> 6;
  const int ln = l & 15, lg = l >> 4;

  const int s_im = t >> 6, s_ln = (t >> 2) & 15, s_lg = t & 3;
  const int a_chunk = (s_im * 64 + s_lg * 16 + s_ln) * 8;
  const int a_row = s_im * 16 + s_ln;

  const u16* bsrc = w2p + (size_t)(j0 + w * 32 + ln) * 32 + lg * 8;  // + ks*1605632 + nf*512
  u16* bdst = smem + w * 1024;

  f32x4 acc[4][2];
  #pragma unroll
  for (int im = 0; im < 4; ++im)
    #pragma unroll
    for (int nf = 0; nf < 2; ++nf) acc[im][nf] = f32x4{0.f, 0.f, 0.f, 0.f};

  // prologue: stage ks=0
  {
    gll16(bsrc,       bdst);
    gll16(bsrc + 512, bdst + 512);
    const float* hs = hbase + (size_t)a_row * 512 + s_lg * 8;
    float4 v0 = *(const float4*)(hs);
    float4 v1 = *(const float4*)(hs + 4);
    float vv[8] = {v0.x, v0.y, v0.z, v0.w, v1.x, v1.y, v1.z, v1.w};
    u16x8 hi, lo;
    #pragma unroll
    for (int jq = 0; jq < 8; ++jq) {
      u16 h = f2bf(vv[jq]);
      hi[jq] = h;
      lo[jq] = f2bf(vv[jq] - bf2f(h));
    }
    *(u16x8*)(smem + 8192 + a_chunk) = hi;
    *(u16x8*)(smem + 8192 + 2048 + a_chunk) = lo;
  }
  __syncthreads();

  for (int ks = 0; ks < 32; ++ks) {
    const int cur = ks & 1;
    if (ks < 31) {
      u16* bd = smem + ((cur ^ 1) << 12) + w * 1024;
      const u16* bs = bsrc + (size_t)(ks + 1) * 1605632;
      gll16(bs, bd);
      gll16(bs + 512, bd + 512);
      const int kn = ks + 1;
      const float* hs = hbase + (kn >= 16 ? 65536 : 0) + (size_t)a_row * 512 + (kn & 15) * 32 + s_lg * 8;
      float4 v0 = *(const float4*)(hs);
      float4 v1 = *(const float4*)(hs + 4);
      float vv[8] = {v0.x, v0.y, v0.z, v0.w, v1.x, v1.y, v1.z, v1.w};
      u16x8 hi, lo;
      #pragma unroll
      for (int jq = 0; jq < 8; ++jq) {
        u16 h = f2bf(vv[jq]);
        hi[jq] = h;
        lo[jq] = f2bf(vv[jq] - bf2f(h));
      }
      u16* An = smem + 8192 + ((cur ^ 1) << 12);
      *(u16x8*)(An + a_chunk) = hi;
      *(u16x8*)(An + 2048 + a_chunk) = lo;
    }
    const u16* Ac = smem + 8192 + (cur << 12);
    const u16* Bc = smem + (cur << 12) + w * 1024;
    bf16x8 ahi[4], alo[4], bfr[2];
    #pragma unroll
    for (int im = 0; im < 4; ++im) {
      ahi[im] = *(const bf16x8*)(Ac + im * 512 + l * 8);
      alo[im] = *(const bf16x8*)(Ac + 2048 + im * 512 + l * 8);
    }
    #pragma unroll
    for (int nf = 0; nf < 2; ++nf) bfr[nf] = *(const bf16x8*)(Bc + nf * 512 + l * 8);
    #pragma unroll
    for (int im = 0; im < 4; ++im)
      #pragma unroll
      for (int nf = 0; nf < 2; ++nf) {
        acc[im][nf] = __builtin_amdgcn_mfma_f32_16x16x32_bf16(alo[im], bfr[nf], acc[im][nf], 0, 0, 0);
        acc[im][nf] = __builtin_amdgcn_mfma_f32_16x16x32_bf16(ahi[im], bfr[nf], acc[im][nf], 0, 0, 0);
      }
    __syncthreads();
  }

  // epilogue: D layout row = im*16 + lg*4 + r (batch), col = j0 + w*32 + nf*16 + ln
  #pragma unroll
  for (int nf = 0; nf < 2; ++nf) {
    int c = j0 + w * 32 + nf * 16 + ln;
    if (c < 50000) {
      float fb = fcb[c];
      #pragma unroll
      for (int im = 0; im < 4; ++im)
        #pragma unroll
        for (int r = 0; r < 4; ++r) {
          int row = im * 16 + lg * 4 + r;
          logits[(size_t)row * 50000 + c] = acc[im][nf][r] + fb;
        }
    }
  }
}

// ---------------- fallback f32 fc (used when ws too small for w2p)
__global__ void __launch_bounds__(256)
k_fc_f32(const float* __restrict__ dout_ro, const float* __restrict__ fcw,
         const float* __restrict__ fcb, float* __restrict__ logits) {
  __shared__ float ol[64][68];
  __shared__ float wl[64][132];
  const int t = threadIdx.x;
  const int j0 = blockIdx.x * 128;
  const int tb = t >> 5, tj = t & 31;
  const float* hf = dout_ro + 3200000u;
  const float* hb = dout_ro + 3200000u + 65536u;
  float acc[8][4];
  #pragma unroll
  for (int bi = 0; bi < 8; ++bi)
    #pragma unroll
    for (int ji = 0; ji < 4; ++ji) acc[bi][ji] = 0.f;

  for (int k0 = 0; k0 < 1024; k0 += 64) {
    __syncthreads();
    {
      int bb = t >> 2, kq = (t & 3) * 16;
      const float* src = (k0 < 512) ? (hf + (size_t)bb * 512 + k0 + kq)
                                    : (hb + (size_t)bb * 512 + (k0 - 512) + kq);
      #pragma unroll
      for (int i = 0; i < 4; ++i) {
        float4 v = *(const float4*)(src + i * 4);
        ol[kq + i*4 + 0][bb] = v.x;
        ol[kq + i*4 + 1][bb] = v.y;
        ol[kq + i*4 + 2][bb] = v.z;
        ol[kq + i*4 + 3][bb] = v.w;
      }
    }
    {
      int kk = t >> 2, jh = (t & 3) * 32;
      const float* wsrc = fcw + (size_t)(k0 + kk) * 50000 + j0 + jh;
      #pragma unroll
      for (int i = 0; i < 8; ++i) {
        int j = j0 + jh + i * 4;
        float4 v;
        if (j + 3 < 50000) {
          v = *(const float4*)(wsrc + i * 4);
        } else {
          v.x = (j + 0 < 50000) ? wsrc[i*4 + 0] : 0.f;
          v.y = (j + 1 < 50000) ? wsrc[i*4 + 1] : 0.f;
          v.z = (j + 2 < 50000) ? wsrc[i*4 + 2] : 0.f;
          v.w = 0.f;
        }
        *(float4*)&wl[kk][jh + i * 4] = v;
      }
    }
    __syncthreads();
    #pragma unroll 4
    for (int kk = 0; kk < 64; ++kk) {
      float4 wv = *(const float4*)&wl[kk][tj * 4];
      float4 q0 = *(const float4*)&ol[kk][tb * 8];
      float4 q1 = *(const float4*)&ol[kk][tb * 8 + 4];
      float obv[8] = {q0.x, q0.y, q0.z, q0.w, q1.x, q1.y, q1.z, q1.w};
      #pragma unroll
      for (int bi = 0; bi < 8; ++bi) {
        acc[bi][0] += obv[bi] * wv.x;
        acc[bi][1] += obv[bi] * wv.y;
        acc[bi][2] += obv[bi] * wv.z;
        acc[bi][3] += obv[bi] * wv.w;
      }
    }
  }

  const int j = j0 + tj * 4;
  if (j + 3 < 50000) {
    float4 fb = *(const float4*)(fcb + j);
    #pragma unroll
    for (int bi = 0; bi < 8; ++bi) {
      float4 r;
      r.x = acc[bi][0] + fb.x; r.y = acc[bi][1] + fb.y;
      r.z = acc[bi][2] + fb.z; r.w = acc[bi][3] + fb.w;
      *(float4*)&logits[(size_t)(tb * 8 + bi) * 50000 + j] = r;
    }
  } else {
    for (int ji = 0; ji < 4; ++ji) {
      if (j + ji < 50000) {
        float fb = fcb[j + ji];
        for (int bi = 0; bi < 8; ++bi)
          logits[(size_t)(tb * 8 + bi) * 50000 + j + ji] = acc[bi][ji] + fb;
      }
    }
  }
}

extern "C" void kernel_launch(void* const* d_in, const int* in_sizes, int n_in,
                              void* d_out, int out_size, void* d_ws, size_t ws_size,
                              hipStream_t stream) {
  const int*   x    = (const int*)  d_in[0];
  const float* cfwd = (const float*)d_in[1];
  const float* cbwd = (const float*)d_in[2];
  const float* enc  = (const float*)d_in[3];
  const float* emb  = (const float*)d_in[4];
  const float* W1w  = (const float*)d_in[5];
  const float* W1b  = (const float*)d_in[6];
  const float* W2w  = (const float*)d_in[7];
  const float* W2b  = (const float*)d_in[8];
  const float* W3w  = (const float*)d_in[9];
  const float* W3b  = (const float*)d_in[10];
  const float* Vw   = (const float*)d_in[11];
  const float* Vb   = (const float*)d_in[12];
  const float* Kf   = (const float*)d_in[13];
  const float* bfv  = (const float*)d_in[14];
  const float* Kb   = (const float*)d_in[15];
  const float* bbv  = (const float*)d_in[16];
  const float* fcw  = (const float*)d_in[17];
  const float* fcb  = (const float*)d_in[18];
  float* out = (float*)d_out;

  const bool haveWs = (ws_size >= SCRATCH_BYTES);
  const bool bigWs  = (ws_size >= TOTAL_BYTES);
  float* S = haveWs ? (float*)d_ws : out;   // fallback carve ends < 3200000 (logits safe)
  u16*   w1p   = (u16*)S;
  float* hpb   = S + OF_HPB;
  float* score = S + OF_SCORE;
  float* xin   = S + OF_XIN;
  float* zpart = S + OF_ZPART;
  u16*   w2p   = (u16*)(S + OF_W2P_F);      // valid only when bigWs

  k_prep_w1<<<128, 256, 0, stream>>>(W1w, w1p);
  k_prep_hp<<<64, 256, 0, stream>>>(cfwd, cbwd, W2w, W2b, W3w, W3b, W1b, hpb);
  if (bigWs) k_prep_fcw<<<6272, 256, 0, stream>>>(fcw, w2p);
  k_score<<<2048, 512, 0, stream>>>(enc, w1p, hpb, Vw, Vb, score);
  k_ctx<<<512, 256, 0, stream>>>(enc, score, xin);
  k_xe<<<64, 256, 0, stream>>>(x, emb, xin);
  k_lstm_gemm<<<256, 256, 0, stream>>>(xin, Kf, Kb, zpart);
  k_gates<<<128, 512, 0, stream>>>(zpart, bfv, bbv, out);
  if (bigWs) k_fc_mfma<<<392, 256, 0, stream>>>(out + 3200000u, w2p, fcb, out);
  else       k_fc_f32<<<391, 256, 0, stream>>>(out, fcw, fcb, out);
}

// Round 7
// 519.707 us; speedup vs baseline: 1.1879x; 1.1879x over previous
//
#include <hip/hip_runtime.h>

using u16 = unsigned short;
typedef float f32x4 __attribute__((ext_vector_type(4)));
typedef __bf16 bf16x8 __attribute__((ext_vector_type(8)));
typedef u16 u16x8 __attribute__((ext_vector_type(8)));
typedef u16 u16x4 __attribute__((ext_vector_type(4)));

// dims: B=64, S=2048, ENC=1024, U=512, E=256, V=50000, IN=1280
// scratch layout (float units)
static constexpr int OF_HPB   = 262144;    // w1p: 512K u16 = 262144 floats
static constexpr int OF_CTXP  = 294912;    // hpb: 64*512
static constexpr int OF_STATS = 2392064;   // ctxp: 2048*1024
static constexpr int OF_XIN   = 2394112;   // stats: 2048
static constexpr int OF_ZPART = 2476032;   // xin: 64*1280
static constexpr int OF_HHL   = 3000320;   // zpart: 4*64*2048; hhl: 2*64*1024 u16
static constexpr size_t SCRATCH_FLOATS = 3065856;
static constexpr size_t SCRATCH_BYTES  = SCRATCH_FLOATS * 4ull;   // ~12.3 MB

__device__ __forceinline__ u16 f2bf(float f) {
  unsigned u = __float_as_uint(f);
  u += 0x7FFFu + ((u >> 16) & 1u);   // RNE; inputs finite
  return (u16)(u >> 16);
}
__device__ __forceinline__ float bf2f(u16 u) {
  return __uint_as_float((unsigned)u << 16);
}
__device__ __forceinline__ float fast_tanh(float x) {
  x = fminf(fmaxf(x, -20.f), 20.f);
  float e = __expf(2.f * x);
  return (e - 1.f) / (e + 1.f);
}
__device__ __forceinline__ float fast_sig(float x) { return 1.f / (1.f + __expf(-x)); }

__device__ __forceinline__ void gll16(const u16* g, u16* l) {
  __builtin_amdgcn_global_load_lds(
      (const __attribute__((address_space(1))) unsigned int*)g,
      (__attribute__((address_space(3))) unsigned int*)l, 16, 0, 0);
}

// ---------------- W1 (1024x512 f32 [k][u]) -> bf16 packed [ks][u][kk], ks=k/32
__global__ void k_prep_w1(const float* __restrict__ W1w, u16* __restrict__ w1p) {
  __shared__ float tile[32][132];
  const int t = threadIdx.x;
  const int ks = blockIdx.x >> 2, u0 = (blockIdx.x & 3) * 128;
  {
    int kk = t >> 3, ui = (t & 7) * 16;
    const float* src = W1w + (size_t)(ks * 32 + kk) * 512 + u0 + ui;
    #pragma unroll
    for (int i = 0; i < 4; ++i)
      *(float4*)&tile[kk][ui + i * 4] = *(const float4*)(src + i * 4);
  }
  __syncthreads();
  {
    int u = t >> 1, kh = (t & 1) * 16;
    u16x8 p0, p1;
    #pragma unroll
    for (int i = 0; i < 8; ++i) {
      p0[i] = f2bf(tile[kh + i][u]);
      p1[i] = f2bf(tile[kh + 8 + i][u]);
    }
    u16* dst = w1p + ((size_t)ks * 512 + u0 + u) * 32 + kh;
    *(u16x8*)(dst)     = p0;
    *(u16x8*)(dst + 8) = p1;
  }
}

// ---------------- hpb[b][u] = c_fwd@W2 + W2_b + c_bwd@W3 + W3_b + W1_b
__global__ void k_prep_hp(const float* __restrict__ cf, const float* __restrict__ cb,
                          const float* __restrict__ W2w, const float* __restrict__ W2b,
                          const float* __restrict__ W3w, const float* __restrict__ W3b,
                          const float* __restrict__ W1b, float* __restrict__ hpb) {
  __shared__ float cfl[512], cbl[512];
  const int b = blockIdx.x, t = threadIdx.x;
  cfl[t] = cf[(size_t)b * 512 + t];       cfl[t + 256] = cf[(size_t)b * 512 + t + 256];
  cbl[t] = cb[(size_t)b * 512 + t];       cbl[t + 256] = cb[(size_t)b * 512 + t + 256];
  __syncthreads();
  const int u1 = t, u2 = t + 256;
  float a1 = W2b[u1] + W3b[u1] + W1b[u1];
  float a2 = W2b[u2] + W3b[u2] + W1b[u2];
  for (int k = 0; k < 512; ++k) {
    float c1 = cfl[k], c2 = cbl[k];
    const float* r2 = W2w + (size_t)k * 512;
    const float* r3 = W3w + (size_t)k * 512;
    a1 += c1 * r2[u1] + c2 * r3[u1];
    a2 += c1 * r2[u2] + c2 * r3[u2];
  }
  hpb[(size_t)b * 512 + u1] = a1;
  hpb[(size_t)b * 512 + u2] = a2;
}

// ---------------- fused attention: score GEMM -> exp/stats -> tail-PV (L3-hot).
// 2048 blocks = 64 b x 32 tiles (64 rows). 512 thr / 8 waves (1M x 8N, wave 64x64).
// LDS 72KB (2 blocks/CU): B dbuf 2x32KB (global_load_lds, read-contiguous chunk
// layout via pre-permuted per-lane source) + A dbuf 2x4KB (reg-staged f32->bf16).
// Plain __syncthreads pipeline (asm-scheduled variant measured +50us, reverted).
__global__ void __launch_bounds__(512, 4)
k_attn(const float* __restrict__ enc, const u16* __restrict__ w1p,
       const float* __restrict__ hpb, const float* __restrict__ Vw,
       const float* __restrict__ Vb, float* __restrict__ ctxp,
       float* __restrict__ stats) {
  __shared__ __align__(16) u16 smem[36864];   // B0[16384] B1[16384] A0[2048] A1[2048]

  const int t = threadIdx.x;
  const int bid = blockIdx.x;
  const int b = bid >> 5, tile = bid & 31;
  const size_t row0 = (size_t)b * 2048 + (size_t)tile * 64;

  const int l = t & 63, w = t >> 6;     // 8 waves; wave w owns cols [w*64, w*64+64)
  const int ln = l & 15, lg = l >> 4;

  // A staging: thread t loads 4 f32 of row (s_im*16+s_ln), k-octet s_lg, half s_h
  const int s_im = t >> 7, s_ln = (t >> 3) & 15, s_lg = (t >> 1) & 3, s_h = t & 1;
  const float* a_src = enc + (row0 + s_im * 16 + s_ln) * 1024 + s_lg * 8 + s_h * 4;
  const int a_dst = (s_im * 64 + s_lg * 16 + s_ln) * 8 + s_h * 4;   // read-contig chunk
  // B staging: per-lane permuted source so linear gll16 writes land read-contiguous
  const u16* bsrc = w1p + (size_t)(w * 64 + ln) * 32 + lg * 8;      // + ks*16384 + nf*512
  u16* bdst = smem + w * 2048;                                       // + (buf<<14) + nf*512

  f32x4 acc[4][4];
  #pragma unroll
  for (int im = 0; im < 4; ++im)
    #pragma unroll
    for (int nf = 0; nf < 4; ++nf) acc[im][nf] = f32x4{0.f, 0.f, 0.f, 0.f};

  // prologue: stage A(0)+B(0) into buf0; A(1) in flight
  float4 avB;
  {
    float4 av0 = *(const float4*)(a_src);
    u16x4 aw;
    aw[0]=f2bf(av0.x); aw[1]=f2bf(av0.y); aw[2]=f2bf(av0.z); aw[3]=f2bf(av0.w);
    *(u16x4*)(smem + 32768 + a_dst) = aw;
    gll16(bsrc,        bdst);
    gll16(bsrc +  512, bdst +  512);
    gll16(bsrc + 1024, bdst + 1024);
    gll16(bsrc + 1536, bdst + 1536);
    avB = *(const float4*)(a_src + 32);
  }
  __syncthreads();

  for (int ks = 0; ks < 32; ++ks) {
    const int cur = ks & 1;
    if (ks < 31) {
      u16* An = smem + 32768 + ((cur ^ 1) << 11);
      u16x4 aw;
      aw[0]=f2bf(avB.x); aw[1]=f2bf(avB.y); aw[2]=f2bf(avB.z); aw[3]=f2bf(avB.w);
      *(u16x4*)(An + a_dst) = aw;
      if (ks < 30) avB = *(const float4*)(a_src + (ks + 2) * 32);   // A(ks+2) in flight
      u16* bd = bdst + ((cur ^ 1) << 14);
      const u16* bs = bsrc + (size_t)(ks + 1) * 16384;
      gll16(bs, bd);               gll16(bs +  512, bd +  512);
      gll16(bs + 1024, bd + 1024); gll16(bs + 1536, bd + 1536);
    }
    const u16* Ac = smem + 32768 + (cur << 11);
    const u16* Bc = smem + (cur << 14) + w * 2048;
    bf16x8 afr[4], bfr[4];
    #pragma unroll
    for (int im = 0; im < 4; ++im) afr[im] = *(const bf16x8*)(Ac + im * 512 + l * 8);
    #pragma unroll
    for (int nf = 0; nf < 4; ++nf) bfr[nf] = *(const bf16x8*)(Bc + nf * 512 + l * 8);
    #pragma unroll
    for (int im = 0; im < 4; ++im)
      #pragma unroll
      for (int nf = 0; nf < 4; ++nf)
        acc[im][nf] = __builtin_amdgcn_mfma_f32_16x16x32_bf16(afr[im], bfr[nf], acc[im][nf], 0, 0, 0);
    __syncthreads();
  }

  // ---- epilogue: score -> exp -> stats (smem reused; GEMM reads done at barrier)
  float* fsm = (float*)smem;
  float* red = fsm;            // [64][9]
  float* scv = fsm + 576;      // [64] exp(score)
  float* pcv = fsm + 640;      // [1024] tail partial

  float vw_l[4], hp_l[4];
  #pragma unroll
  for (int nf = 0; nf < 4; ++nf) {
    int col = w * 64 + nf * 16 + ln;
    vw_l[nf] = Vw[col];
    hp_l[nf] = hpb[(size_t)b * 512 + col];
  }
  #pragma unroll
  for (int im = 0; im < 4; ++im) {
    #pragma unroll
    for (int r = 0; r < 4; ++r) {
      float s = 0.f;
      #pragma unroll
      for (int nf = 0; nf < 4; ++nf)
        s += vw_l[nf] * fast_tanh(acc[im][nf][r] + hp_l[nf]);
      s += __shfl_xor(s, 1);
      s += __shfl_xor(s, 2);
      s += __shfl_xor(s, 4);
      s += __shfl_xor(s, 8);
      if (ln == 0) red[(im * 16 + lg * 4 + r) * 9 + w] = s;
    }
  }
  __syncthreads();
  if (t < 64) {
    float s = Vb[0];
    #pragma unroll
    for (int w2 = 0; w2 < 8; ++w2) s += red[t * 9 + w2];
    float e = __expf(s);   // |score| bounded (~||Vw||_1): f32-safe without max-sub
    scv[t] = e;
    float p = e;
    p += __shfl_xor(p, 1);  p += __shfl_xor(p, 2);  p += __shfl_xor(p, 4);
    p += __shfl_xor(p, 8);  p += __shfl_xor(p, 16); p += __shfl_xor(p, 32);
    if (t == 0) stats[bid] = p;
  }
  __syncthreads();

  // ---- tail-PV: unnormalized partial ctx from own (L3-hot) f32 enc tile
  {
    const int c4 = (t & 255) * 4;
    const int rh = t >> 8;                 // 0/1 -> rows rh*32..+32
    const float* ep = enc + (row0 + rh * 32) * 1024 + c4;
    float ax = 0.f, ay = 0.f, az = 0.f, aw2 = 0.f;
    #pragma unroll 4
    for (int r = 0; r < 32; ++r) {
      float4 v = *(const float4*)(ep + (size_t)r * 1024);
      float s = scv[rh * 32 + r];
      ax += s * v.x; ay += s * v.y; az += s * v.z; aw2 += s * v.w;
    }
    if (t >= 256) {
      float4 st = {ax, ay, az, aw2};
      *(float4*)&pcv[c4] = st;
    }
    __syncthreads();
    if (t < 256) {
      float4 p2 = *(const float4*)&pcv[c4];
      float4 o = {ax + p2.x, ay + p2.y, az + p2.z, aw2 + p2.w};
      *(float4*)&ctxp[(size_t)bid * 1024 + c4] = o;
    }
  }
}

// ---------------- combine tile partials -> xin[:, :1024]; gather emb -> xin[:, 1024:]
__global__ void k_attn_reduce(const float* __restrict__ ctxp, const float* __restrict__ stats,
                              const int* __restrict__ x, const float* __restrict__ emb,
                              float* __restrict__ xin) {
  __shared__ float ps[32];
  __shared__ float invs;
  const int b = blockIdx.x, t = threadIdx.x;
  if (t < 32) ps[t] = stats[b * 32 + t];
  __syncthreads();
  if (t == 0) {
    float s = 0.f;
    #pragma unroll
    for (int i = 0; i < 32; ++i) s += ps[i];
    invs = 1.f / s;
  }
  __syncthreads();
  const float inv = invs;
  #pragma unroll
  for (int i = 0; i < 4; ++i) {
    int c = t + i * 256;
    float a = 0.f;
    for (int chv = 0; chv < 32; ++chv)
      a += ctxp[((size_t)b * 32 + chv) * 1024 + c];
    xin[(size_t)b * 1280 + c] = a * inv;
  }
  xin[(size_t)b * 1280 + 1024 + t] = emb[(size_t)x[b] * 256 + t];
}

// ---------------- z_part = xin @ K  (dir x ksplit x jtile), f32
__global__ void k_lstm_gemm(const float* __restrict__ xin, const float* __restrict__ Kf,
                            const float* __restrict__ Kb, float* __restrict__ zpart) {
  __shared__ float xl[32][68];   // [kk][b], padded
  const int t = threadIdx.x;
  const int bid = blockIdx.x;          // 2 dir * 64 jt * 2 ks = 256
  const int dir = bid >> 7;
  const int jt  = (bid >> 1) & 63;
  const int ks  = bid & 1;
  const float* K = dir ? Kb : Kf;
  const int j  = jt * 32 + (t & 31);
  const int tb = t >> 5;               // 8 groups of 8 b
  const int brow = t >> 2, kq = (t & 3) * 8;
  float acc[8] = {0,0,0,0,0,0,0,0};
  for (int k0 = ks * 640; k0 < ks * 640 + 640; k0 += 32) {
    float4 x0 = *(const float4*)&xin[(size_t)brow * 1280 + k0 + kq];
    float4 x1 = *(const float4*)&xin[(size_t)brow * 1280 + k0 + kq + 4];
    __syncthreads();
    xl[kq+0][brow]=x0.x; xl[kq+1][brow]=x0.y; xl[kq+2][brow]=x0.z; xl[kq+3][brow]=x0.w;
    xl[kq+4][brow]=x1.x; xl[kq+5][brow]=x1.y; xl[kq+6][brow]=x1.z; xl[kq+7][brow]=x1.w;
    __syncthreads();
    const float* Kp = K + (size_t)k0 * 2048 + j;
    #pragma unroll 8
    for (int kk = 0; kk < 32; ++kk) {
      float wv = Kp[(size_t)kk * 2048];
      float4 v0 = *(const float4*)&xl[kk][tb * 8];
      float4 v1 = *(const float4*)&xl[kk][tb * 8 + 4];
      acc[0] += v0.x * wv; acc[1] += v0.y * wv; acc[2] += v0.z * wv; acc[3] += v0.w * wv;
      acc[4] += v1.x * wv; acc[5] += v1.y * wv; acc[6] += v1.z * wv; acc[7] += v1.w * wv;
    }
  }
  float* zp = zpart + ((size_t)dir * 2 + ks) * 64 * 2048;
  #pragma unroll
  for (int i = 0; i < 8; ++i)
    zp[(size_t)(tb * 8 + i) * 2048 + j] = acc[i];
}

// ---------------- gates: c = sig(i)*tanh(g); h = sig(o)*tanh(c); also h -> hi/lo bf16
__global__ void k_gates(const float* __restrict__ zpart, const float* __restrict__ bfv,
                        const float* __restrict__ bbv, float* __restrict__ dout,
                        u16* __restrict__ hhl) {
  const int dir = blockIdx.x >> 6, b = blockIdx.x & 63, u = threadIdx.x;
  const float* bias = dir ? bbv : bfv;
  const float* z0 = zpart + ((size_t)dir * 2 + 0) * 131072 + (size_t)b * 2048;
  const float* z1 = zpart + ((size_t)dir * 2 + 1) * 131072 + (size_t)b * 2048;
  float zi = z0[u]        + z1[u]        + bias[u];
  float zg = z0[1024 + u] + z1[1024 + u] + bias[1024 + u];
  float zo = z0[1536 + u] + z1[1536 + u] + bias[1536 + u];
  float c = fast_sig(zi) * fast_tanh(zg);
  float h = fast_sig(zo) * fast_tanh(c);
  size_t base = 3200000u + (size_t)dir * 65536u;
  dout[base + (size_t)b * 512 + u] = h;
  dout[base + 32768u + (size_t)b * 512 + u] = c;
  u16 hi = f2bf(h);
  u16 lo = f2bf(h - bf2f(hi));
  hhl[(size_t)b * 1024 + dir * 512 + u] = hi;
  hhl[65536u + (size_t)b * 1024 + dir * 512 + u] = lo;
}

// ---------------- logits = [hf hb] @ fc_w + fc_b  via MFMA, fcw read DIRECTLY as f32
// (fc runs once -> pre-packing costs more HBM than it saves). 392 blocks x 128 cols,
// 256 thr / 4 waves (1M x 4N, wave 64x32). B: f32 tile -> LDS [32][136] -> transpose-
// read + cvt to bf16 regs. A: h hi/lo bf16 direct from L2-hot hhl. HBM floor 200MB.
__global__ void __launch_bounds__(256)
k_fc_mfma(const float* __restrict__ fcw, const u16* __restrict__ hhl,
          const float* __restrict__ fcb, float* __restrict__ logits) {
  __shared__ float Bs[2][32 * 136];
  const int t = threadIdx.x;
  const int j0 = blockIdx.x * 128;
  const int l = t & 63, w = t >> 6;
  const int ln = l & 15, lg = l >> 4;
  const int srow = t >> 3, scol = (t & 7) * 16;
  const bool interior = (j0 + 128 <= 50000);

  f32x4 acc[4][2];
  #pragma unroll
  for (int im = 0; im < 4; ++im)
    #pragma unroll
    for (int nf = 0; nf < 2; ++nf) acc[im][nf] = f32x4{0.f, 0.f, 0.f, 0.f};

  float4 pre[4];
  // prologue: load+stage ks=0
  {
    const float* src = fcw + (size_t)srow * 50000 + j0 + scol;
    if (interior) {
      #pragma unroll
      for (int q = 0; q < 4; ++q) pre[q] = *(const float4*)(src + q * 4);
    } else {
      #pragma unroll
      for (int q = 0; q < 4; ++q) {
        int jb = j0 + scol + q * 4;
        pre[q].x = (jb + 0 < 50000) ? src[q*4 + 0] : 0.f;
        pre[q].y = (jb + 1 < 50000) ? src[q*4 + 1] : 0.f;
        pre[q].z = (jb + 2 < 50000) ? src[q*4 + 2] : 0.f;
        pre[q].w = (jb + 3 < 50000) ? src[q*4 + 3] : 0.f;
      }
    }
    #pragma unroll
    for (int q = 0; q < 4; ++q)
      *(float4*)&Bs[0][srow * 136 + scol + q * 4] = pre[q];
  }
  __syncthreads();

  for (int ks = 0; ks < 32; ++ks) {
    const int cur = ks & 1;
    if (ks < 31) {   // load next B tile to regs (hides under compute)
      const float* src = fcw + (size_t)(ks + 1) * 32 * 50000 + (size_t)srow * 50000 + j0 + scol;
      if (interior) {
        #pragma unroll
        for (int q = 0; q < 4; ++q) pre[q] = *(const float4*)(src + q * 4);
      } else {
        #pragma unroll
        for (int q = 0; q < 4; ++q) {
          int jb = j0 + scol + q * 4;
          pre[q].x = (jb + 0 < 50000) ? src[q*4 + 0] : 0.f;
          pre[q].y = (jb + 1 < 50000) ? src[q*4 + 1] : 0.f;
          pre[q].z = (jb + 2 < 50000) ? src[q*4 + 2] : 0.f;
          pre[q].w = (jb + 3 < 50000) ? src[q*4 + 3] : 0.f;
        }
      }
    }
    // A fragments: hi/lo direct from global (L2-hot, 256KB total)
    bf16x8 ahi[4], alo[4];
    #pragma unroll
    for (int im = 0; im < 4; ++im) {
      const u16* ha = hhl + (size_t)(im * 16 + ln) * 1024 + ks * 32 + lg * 8;
      ahi[im] = *(const bf16x8*)(ha);
      alo[im] = *(const bf16x8*)(ha + 65536);
    }
    // B fragments: transpose-read f32 from LDS, cvt to bf16
    bf16x8 bfr[2];
    #pragma unroll
    for (int nf = 0; nf < 2; ++nf) {
      u16x8 pv;
      #pragma unroll
      for (int i = 0; i < 8; ++i)
        pv[i] = f2bf(Bs[cur][(lg * 8 + i) * 136 + w * 32 + nf * 16 + ln]);
      bfr[nf] = *(bf16x8*)&pv;
    }
    #pragma unroll
    for (int im = 0; im < 4; ++im)
      #pragma unroll
      for (int nf = 0; nf < 2; ++nf) {
        acc[im][nf] = __builtin_amdgcn_mfma_f32_16x16x32_bf16(alo[im], bfr[nf], acc[im][nf], 0, 0, 0);
        acc[im][nf] = __builtin_amdgcn_mfma_f32_16x16x32_bf16(ahi[im], bfr[nf], acc[im][nf], 0, 0, 0);
      }
    if (ks < 31) {
      #pragma unroll
      for (int q = 0; q < 4; ++q)
        *(float4*)&Bs[cur ^ 1][srow * 136 + scol + q * 4] = pre[q];
    }
    __syncthreads();
  }

  // epilogue: D row = im*16 + lg*4 + r (batch), col = j0 + w*32 + nf*16 + ln
  #pragma unroll
  for (int nf = 0; nf < 2; ++nf) {
    int c = j0 + w * 32 + nf * 16 + ln;
    if (c < 50000) {
      float fb = fcb[c];
      #pragma unroll
      for (int im = 0; im < 4; ++im)
        #pragma unroll
        for (int r = 0; r < 4; ++r) {
          int row = im * 16 + lg * 4 + r;
          logits[(size_t)row * 50000 + c] = acc[im][nf][r] + fb;
        }
    }
  }
}

// ---------------- fallback f32 fc (used when ws too small for scratch arena)
__global__ void __launch_bounds__(256)
k_fc_f32(const float* __restrict__ dout_ro, const float* __restrict__ fcw,
         const float* __restrict__ fcb, float* __restrict__ logits) {
  __shared__ float ol[64][68];
  __shared__ float wl[64][132];
  const int t = threadIdx.x;
  const int j0 = blockIdx.x * 128;
  const int tb = t >> 5, tj = t & 31;
  const float* hf = dout_ro + 3200000u;
  const float* hb = dout_ro + 3200000u + 65536u;
  float acc[8][4];
  #pragma unroll
  for (int bi = 0; bi < 8; ++bi)
    #pragma unroll
    for (int ji = 0; ji < 4; ++ji) acc[bi][ji] = 0.f;

  for (int k0 = 0; k0 < 1024; k0 += 64) {
    __syncthreads();
    {
      int bb = t >> 2, kq = (t & 3) * 16;
      const float* src = (k0 < 512) ? (hf + (size_t)bb * 512 + k0 + kq)
                                    : (hb + (size_t)bb * 512 + (k0 - 512) + kq);
      #pragma unroll
      for (int i = 0; i < 4; ++i) {
        float4 v = *(const float4*)(src + i * 4);
        ol[kq + i*4 + 0][bb] = v.x;
        ol[kq + i*4 + 1][bb] = v.y;
        ol[kq + i*4 + 2][bb] = v.z;
        ol[kq + i*4 + 3][bb] = v.w;
      }
    }
    {
      int kk = t >> 2, jh = (t & 3) * 32;
      const float* wsrc = fcw + (size_t)(k0 + kk) * 50000 + j0 + jh;
      #pragma unroll
      for (int i = 0; i < 8; ++i) {
        int j = j0 + jh + i * 4;
        float4 v;
        if (j + 3 < 50000) {
          v = *(const float4*)(wsrc + i * 4);
        } else {
          v.x = (j + 0 < 50000) ? wsrc[i*4 + 0] : 0.f;
          v.y = (j + 1 < 50000) ? wsrc[i*4 + 1] : 0.f;
          v.z = (j + 2 < 50000) ? wsrc[i*4 + 2] : 0.f;
          v.w = 0.f;
        }
        *(float4*)&wl[kk][jh + i * 4] = v;
      }
    }
    __syncthreads();
    #pragma unroll 4
    for (int kk = 0; kk < 64; ++kk) {
      float4 wv = *(const float4*)&wl[kk][tj * 4];
      float4 q0 = *(const float4*)&ol[kk][tb * 8];
      float4 q1 = *(const float4*)&ol[kk][tb * 8 + 4];
      float obv[8] = {q0.x, q0.y, q0.z, q0.w, q1.x, q1.y, q1.z, q1.w};
      #pragma unroll
      for (int bi = 0; bi < 8; ++bi) {
        acc[bi][0] += obv[bi] * wv.x;
        acc[bi][1] += obv[bi] * wv.y;
        acc[bi][2] += obv[bi] * wv.z;
        acc[bi][3] += obv[bi] * wv.w;
      }
    }
  }

  const int j = j0 + tj * 4;
  if (j + 3 < 50000) {
    float4 fb = *(const float4*)(fcb + j);
    #pragma unroll
    for (int bi = 0; bi < 8; ++bi) {
      float4 r;
      r.x = acc[bi][0] + fb.x; r.y = acc[bi][1] + fb.y;
      r.z = acc[bi][2] + fb.z; r.w = acc[bi][3] + fb.w;
      *(float4*)&logits[(size_t)(tb * 8 + bi) * 50000 + j] = r;
    }
  } else {
    for (int ji = 0; ji < 4; ++ji) {
      if (j + ji < 50000) {
        float fb = fcb[j + ji];
        for (int bi = 0; bi < 8; ++bi)
          logits[(size_t)(tb * 8 + bi) * 50000 + j + ji] = acc[bi][ji] + fb;
      }
    }
  }
}

extern "C" void kernel_launch(void* const* d_in, const int* in_sizes, int n_in,
                              void* d_out, int out_size, void* d_ws, size_t ws_size,
                              hipStream_t stream) {
  const int*   x    = (const int*)  d_in[0];
  const float* cfwd = (const float*)d_in[1];
  const float* cbwd = (const float*)d_in[2];
  const float* enc  = (const float*)d_in[3];
  const float* emb  = (const float*)d_in[4];
  const float* W1w  = (const float*)d_in[5];
  const float* W1b  = (const float*)d_in[6];
  const float* W2w  = (const float*)d_in[7];
  const float* W2b  = (const float*)d_in[8];
  const float* W3w  = (const float*)d_in[9];
  const float* W3b  = (const float*)d_in[10];
  const float* Vw   = (const float*)d_in[11];
  const float* Vb   = (const float*)d_in[12];
  const float* Kf   = (const float*)d_in[13];
  const float* bfv  = (const float*)d_in[14];
  const float* Kb   = (const float*)d_in[15];
  const float* bbv  = (const float*)d_in[16];
  const float* fcw  = (const float*)d_in[17];
  const float* fcb  = (const float*)d_in[18];
  float* out = (float*)d_out;

  const bool haveWs = (ws_size >= SCRATCH_BYTES);
  float* S = haveWs ? (float*)d_ws : out;   // fallback carve ends 3065856 < 3200000
  u16*   w1p   = (u16*)S;
  float* hpb   = S + OF_HPB;
  float* ctxp  = S + OF_CTXP;
  float* stats = S + OF_STATS;
  float* xin   = S + OF_XIN;
  float* zpart = S + OF_ZPART;
  u16*   hhl   = (u16*)(S + OF_HHL);

  k_prep_w1<<<128, 256, 0, stream>>>(W1w, w1p);
  k_prep_hp<<<64, 256, 0, stream>>>(cfwd, cbwd, W2w, W2b, W3w, W3b, W1b, hpb);
  k_attn<<<2048, 512, 0, stream>>>(enc, w1p, hpb, Vw, Vb, ctxp, stats);
  k_attn_reduce<<<64, 256, 0, stream>>>(ctxp, stats, x, emb, xin);
  k_lstm_gemm<<<256, 256, 0, stream>>>(xin, Kf, Kb, zpart);
  k_gates<<<128, 512, 0, stream>>>(zpart, bfv, bbv, out, hhl);
  // fc: MFMA path reads hhl from scratch; in fallback mode hhl aliases the logits
  // region (write/read race with fc_mfma) -> use the self-contained f32 fc there.
  if (haveWs) k_fc_mfma<<<392, 256, 0, stream>>>(fcw, hhl, fcb, out);
  else        k_fc_f32<<<391, 256, 0, stream>>>(out, fcw, fcb, out);
}